// Round 5
// baseline (348.241 us; speedup 1.0000x reference)
//
#include <hip/hip_runtime.h>

// Problem constants
#define BB 16
#define NL 256
#define RR 24
#define LL 32
#define NN (NL*NL)        // 65536
#define BNN (BB*NN)       // 1048576
#define TT 64             // FW tile

// Output layout (float32), reference return order.
#define O_TDT 0
#define O_RT  16
#define O_TAT 32
#define O_TD  96
#define O_UNS 112
#define O_TTR 128
#define O_TT  144
#define O_ND  1048720

// Packed (dist, hops) in one f64: v = dist + hops * 2^-30.
// dists exact multiples of 2^-17; hops << 2^13; dist < 2^23 -> packing exact
// in 53-bit mantissa; f64 add distributes; f64 min = lexicographic.
#define HSC 9.3132257461547852e-10   // 2^-30
#define H2  1073741824.0             // 2^30
#define HMASK 8191

// LDS: rows of 64 doubles, 16B (double2) chunks XOR-swizzled by row.
#define RIDX(r, c2) (((r)<<6) + ((((c2) ^ ((r)&31)))<<1))
#define LDD(A, r, c2) (*(double2*)&A[RIDX((r),(c2))])

// ---------------- tiny pre-kernel: zero the per-batch barrier counters -------
__global__ __launch_bounds__(512) void k_init0(unsigned* __restrict__ ctr){
    ctr[threadIdx.x] = 0u;
}

// ---- per-batch 16-block barrier (device-scope release/acquire) --------------
// All 256 blocks are co-resident (256 blocks x 256 thr, 64KB LDS -> >=1/CU).
static __device__ __forceinline__ void bbar(unsigned* c, unsigned tgt){
    __syncthreads();
    if (threadIdx.x == 0){
        __hip_atomic_fetch_add(c, 1u, __ATOMIC_RELEASE, __HIP_MEMORY_SCOPE_AGENT);
        while (__hip_atomic_load(c, __ATOMIC_ACQUIRE, __HIP_MEMORY_SCOPE_AGENT) < tgt)
            __builtin_amdgcn_s_sleep(2);
    }
    __syncthreads();
}

// ---- generic 64x64 min-plus multiply-accumulate into regs -------------------
// dd = min(dd, A (x) B); 4x4 per thread, chunk ownership {cA, cA+16} keeps
// same-row B-reads on 16 consecutive chunks (2-way bank conflict max).
static __device__ __forceinline__ void mulAcc(double dd[4][4], double* A, double* Bm,
                                              int r0, int cA, int cB){
    #pragma unroll 4
    for (int q4 = 0; q4 < 16; q4++){
        int kr = q4*4, kc = q4*2;
        double a[4][4], bm[4][4];
        #pragma unroll
        for (int i = 0; i < 4; i++){
            double2 a0 = LDD(A, r0+i, kc), a1 = LDD(A, r0+i, kc+1);
            a[i][0]=a0.x; a[i][1]=a0.y; a[i][2]=a1.x; a[i][3]=a1.y;
        }
        #pragma unroll
        for (int q = 0; q < 4; q++){
            double2 b0 = LDD(Bm, kr+q, cA), b1 = LDD(Bm, kr+q, cB);
            bm[q][0]=b0.x; bm[q][1]=b0.y; bm[q][2]=b1.x; bm[q][3]=b1.y;
        }
        #pragma unroll
        for (int q = 0; q < 4; q++)
        #pragma unroll
        for (int i = 0; i < 4; i++)
        #pragma unroll
        for (int j = 0; j < 4; j++)
            dd[i][j] = fmin(dd[i][j], a[i][q] + bm[q][j]);
    }
}

// ---- in-LDS hierarchical closure of a 64x64 tile (sub-tile 16, 4 rounds) ----
static __device__ __forceinline__ void close64(double* SA, int t, int r0, int cA, int cB){
    for (int skb = 0; skb < 4; skb++){
        int s0 = skb*16, sc2 = skb*8;
        // p1: wave 0 closes the 16x16 diag sub-tile via shfl (no barriers)
        if (t < 64){
            int i = t >> 2, jg = t & 3, rr = s0 + i, cbk = sc2 + jg*2;
            double2 m0 = LDD(SA, rr, cbk), m1 = LDD(SA, rr, cbk+1);
            double md4[4] = {m0.x, m0.y, m1.x, m1.y};
            #pragma unroll
            for (int k = 0; k < 16; k++){
                double rd[4];
                #pragma unroll
                for (int c = 0; c < 4; c++) rd[c] = __shfl(md4[c], (k<<2)|jg);
                double cd = __shfl(md4[k&3], (i<<2)|(k>>2));
                #pragma unroll
                for (int c = 0; c < 4; c++) md4[c] = fmin(md4[c], cd + rd[c]);
            }
            LDD(SA, rr, cbk)   = make_double2(md4[0], md4[1]);
            LDD(SA, rr, cbk+1) = make_double2(md4[2], md4[3]);
        }
        __syncthreads();
        // p2: strips as 2x4 register tiles. t<128: row strip (16 band rows x
        // 64 cols); t>=128: col strip (64 rows x 16 band cols). Band-square
        // double-write is a benign same-value race (both sides compute the
        // closed-square no-op value).
        double sv[2][4], av[2][16];
        int wr, wcA, wcB;
        if (t < 128){
            wr  = s0 + ((t >> 4) << 1);
            wcA = t & 15; wcB = wcA + 16;
        } else {
            int t2 = t - 128;
            wr  = (t2 >> 2) << 1;
            wcA = sc2 + (t2 & 3); wcB = wcA + 4;
        }
        #pragma unroll
        for (int i = 0; i < 2; i++){
            double2 v0 = LDD(SA, wr+i, wcA), v1 = LDD(SA, wr+i, wcB);
            sv[i][0]=v0.x; sv[i][1]=v0.y; sv[i][2]=v1.x; sv[i][3]=v1.y;
            #pragma unroll
            for (int c = 0; c < 8; c++){
                double2 av2 = LDD(SA, wr+i, sc2 + c);
                av[i][2*c] = av2.x; av[i][2*c+1] = av2.y;
            }
        }
        #pragma unroll
        for (int k = 0; k < 16; k++){
            double2 b0 = LDD(SA, s0+k, wcA), b1 = LDD(SA, s0+k, wcB);
            #pragma unroll
            for (int i = 0; i < 2; i++){
                double ak = av[i][k];
                sv[i][0] = fmin(sv[i][0], ak + b0.x);
                sv[i][1] = fmin(sv[i][1], ak + b0.y);
                sv[i][2] = fmin(sv[i][2], ak + b1.x);
                sv[i][3] = fmin(sv[i][3], ak + b1.y);
            }
        }
        __syncthreads();   // all p2 reads done
        #pragma unroll
        for (int i = 0; i < 2; i++){
            LDD(SA, wr+i, wcA) = make_double2(sv[i][0], sv[i][1]);
            LDD(SA, wr+i, wcB) = make_double2(sv[i][2], sv[i][3]);
        }
        __syncthreads();
        // p3: full 64x64, 4x4 per thread, k over the closed band
        double e[4][4];
        #pragma unroll
        for (int i = 0; i < 4; i++){
            double2 v0 = LDD(SA, r0+i, cA), v1 = LDD(SA, r0+i, cB);
            e[i][0]=v0.x; e[i][1]=v0.y; e[i][2]=v1.x; e[i][3]=v1.y;
        }
        #pragma unroll
        for (int q4 = 0; q4 < 4; q4++){
            int kr = s0 + q4*4, kc = sc2 + q4*2;
            double a[4][4], bm[4][4];
            #pragma unroll
            for (int i = 0; i < 4; i++){
                double2 a0 = LDD(SA, r0+i, kc), a1 = LDD(SA, r0+i, kc+1);
                a[i][0]=a0.x; a[i][1]=a0.y; a[i][2]=a1.x; a[i][3]=a1.y;
            }
            #pragma unroll
            for (int q = 0; q < 4; q++){
                double2 b0 = LDD(SA, kr+q, cA), b1 = LDD(SA, kr+q, cB);
                bm[q][0]=b0.x; bm[q][1]=b0.y; bm[q][2]=b1.x; bm[q][3]=b1.y;
            }
            #pragma unroll
            for (int q = 0; q < 4; q++)
            #pragma unroll
            for (int i = 0; i < 4; i++)
            #pragma unroll
            for (int j = 0; j < 4; j++)
                e[i][j] = fmin(e[i][j], a[i][q] + bm[q][j]);
        }
        __syncthreads();   // all p3 reads done
        #pragma unroll
        for (int i = 0; i < 4; i++){
            LDD(SA, r0+i, cA) = make_double2(e[i][0], e[i][1]);
            LDD(SA, r0+i, cB) = make_double2(e[i][2], e[i][3]);
        }
        __syncthreads();
    }
}

// ---------------- the whole pipeline in ONE dispatch -------------------------
// 256 blocks (batch b = blk>>4, tile m = blk&15), 256 threads. Each block owns
// tile (ti,tj) of batch b in registers dd[4][4], write-through to global when
// another block will read it. Per-batch barriers only (batches independent).
__global__ __launch_bounds__(256, 1) void k_mega(
        const float* __restrict__ dtm, const int* __restrict__ routes,
        const float* __restrict__ demand, double* __restrict__ D,
        float* __restrict__ out, float* __restrict__ acc, unsigned* __restrict__ ctr){
    int blk = blockIdx.x;
    int b = blk >> 4, m = blk & 15;
    int ti = m >> 2, tj = m & 3;
    int t  = threadIdx.x;
    int r0 = (t >> 4) << 2;          // 4 owned rows
    int cA = t & 15, cB = cA + 16;   // owned chunks {cA, cA+16}
    unsigned* cbp = ctr + b*32;
    double* Tg = D + b*NN + (ti*NL + tj)*TT;   // own tile in global
    __shared__ __align__(16) double SA[4096], SB[4096];

    // ---- P1: init own tile (INF, diag=0) in global; zero acc ----
    double inf = __builtin_huge_val();
    #pragma unroll
    for (int i = 0; i < 4; i++){
        double2 z0 = make_double2(inf, inf), z1 = z0;
        if (ti == tj){
            int gr = r0 + i;
            if (gr == 2*cA)   z0.x = 0.0;
            if (gr == 2*cA+1) z0.y = 0.0;
            if (gr == 2*cB)   z1.x = 0.0;
            if (gr == 2*cB+1) z1.y = 0.0;
        }
        *(double2*)(Tg + (r0+i)*NL + 2*cA) = z0;
        *(double2*)(Tg + (r0+i)*NL + 2*cB) = z1;
    }
    if (m == 0 && t < 16) acc[b*16 + t] = 0.f;
    bbar(cbp, 16u*1);

    // ---- P2: routes (wave 0: r=m; wave 1: r=16+m if m<8); serial cumsum to
    // match reference f32 cumsum rounding exactly ----
    {
        int w = t >> 6, lane = t & 63;
        int r = (w == 0) ? m : ((w == 1 && m < 8) ? 16 + m : -1);
        char* rbase = (char*)SA + w*1024;
        int*   sS = (int*)rbase;
        float* lf = (float*)(rbase + 128);
        float* lr = (float*)(rbase + 256);
        float* cf = (float*)(rbase + 384);
        float* cr = (float*)(rbase + 512);
        if (r >= 0 && lane < LL) sS[lane] = routes[(b*RR + r)*LL + lane];
        __syncthreads();
        if (r >= 0 && lane < LL-1){
            int a0 = sS[lane], a1 = sS[lane+1];
            const float* dt = dtm + b*NN;
            lf[lane] = dt[a0*NL + a1] + 60.0f;   // MEAN_STOP_TIME_S
            lr[lane] = dt[a1*NL + a0] + 60.0f;
        }
        __syncthreads();
        if (r >= 0 && lane == 0){
            float af = 0.f, ar2 = 0.f;
            cf[0] = 0.f; cr[0] = 0.f;
            for (int l = 0; l < LL-1; l++){
                af += lf[l]; ar2 += lr[l];
                cf[l+1] = af; cr[l+1] = ar2;
            }
            atomicAdd(&acc[b*16 + 1], af + ar2);  // total_route_time
        }
        __syncthreads();
        if (r >= 0){
            unsigned long long* db = (unsigned long long*)(D + b*NN);
            for (int p = lane; p < LL*LL; p += 64){
                int i = p >> 5, j = p & 31;
                if (j > i){
                    double vf = (double)(cf[j] - cf[i]) + HSC;   // hops = 1
                    double vr = (double)(cr[j] - cr[i]) + HSC;
                    atomicMin(&db[sS[i]*NL + sS[j]], (unsigned long long)__double_as_longlong(vf));
                    atomicMin(&db[sS[j]*NL + sS[i]], (unsigned long long)__double_as_longlong(vr));
                }
            }
        }
    }
    bbar(cbp, 16u*2);

    // ---- load own tile into registers (post-routes) ----
    double dd[4][4];
    #pragma unroll
    for (int i = 0; i < 4; i++){
        double2 v0 = *(const double2*)(Tg + (r0+i)*NL + 2*cA);
        double2 v1 = *(const double2*)(Tg + (r0+i)*NL + 2*cB);
        dd[i][0]=v0.x; dd[i][1]=v0.y; dd[i][2]=v1.x; dd[i][3]=v1.y;
    }

    // ---- blocked Floyd-Warshall: fused diag+panel (DP) then inner (I) ----
    for (int kb = 0; kb < 4; kb++){
        bool isDiag = (ti == kb) & (tj == kb);
        bool isRow  = (ti == kb) && !isDiag;
        bool isCol  = (tj == kb) && !isDiag;
        bool inDP   = isDiag | isRow | isCol;
        if (inDP){
            if (isDiag){   // stage own regs as the K tile
                #pragma unroll
                for (int i = 0; i < 4; i++){
                    LDD(SA, r0+i, cA) = make_double2(dd[i][0], dd[i][1]);
                    LDD(SA, r0+i, cB) = make_double2(dd[i][2], dd[i][3]);
                }
            } else {       // stage own regs as operand; K tile from global
                #pragma unroll
                for (int i = 0; i < 4; i++){
                    LDD(SB, r0+i, cA) = make_double2(dd[i][0], dd[i][1]);
                    LDD(SB, r0+i, cB) = make_double2(dd[i][2], dd[i][3]);
                }
                const double* Kg = D + b*NN + kb*TT*(NL+1);
                #pragma unroll
                for (int u = 0; u < 8; u++){
                    int fid = u*256 + t, row = fid >> 5, cc = fid & 31;
                    LDD(SA, row, cc) = *(const double2*)(Kg + row*NL + cc*2);
                }
            }
            __syncthreads();
            close64(SA, t, r0, cA, cB);   // redundant in 7 blocks (parallel)
            if (isDiag){
                #pragma unroll
                for (int i = 0; i < 4; i++){
                    double2 v0 = LDD(SA, r0+i, cA), v1 = LDD(SA, r0+i, cB);
                    dd[i][0]=v0.x; dd[i][1]=v0.y; dd[i][2]=v1.x; dd[i][3]=v1.y;
                }
            } else if (isRow){
                mulAcc(dd, SA, SB, r0, cA, cB);   // O = min(O, K* (x) O)
            } else {
                mulAcc(dd, SB, SA, r0, cA, cB);   // O = min(O, O (x) K*)
            }
            #pragma unroll
            for (int i = 0; i < 4; i++){
                *(double2*)(Tg + (r0+i)*NL + 2*cA) = make_double2(dd[i][0], dd[i][1]);
                *(double2*)(Tg + (r0+i)*NL + 2*cB) = make_double2(dd[i][2], dd[i][3]);
            }
        }
        bbar(cbp, 16u*(3 + 2*kb));
        if (!inDP){
            const double* Xg = D + b*NN + (ti*NL + kb)*TT;
            const double* Yg = D + b*NN + (kb*NL + tj)*TT;
            #pragma unroll
            for (int u = 0; u < 8; u++){
                int fid = u*256 + t, row = fid >> 5, cc = fid & 31;
                LDD(SA, row, cc) = *(const double2*)(Xg + row*NL + cc*2);
                LDD(SB, row, cc) = *(const double2*)(Yg + row*NL + cc*2);
            }
            __syncthreads();
            mulAcc(dd, SA, SB, r0, cA, cB);       // O = min(O, X (x) Y)
            if (kb != 3){
                #pragma unroll
                for (int i = 0; i < 4; i++){
                    *(double2*)(Tg + (r0+i)*NL + 2*cA) = make_double2(dd[i][0], dd[i][1]);
                    *(double2*)(Tg + (r0+i)*NL + 2*cB) = make_double2(dd[i][2], dd[i][3]);
                }
            }
        }
        bbar(cbp, 16u*(4 + 2*kb));
    }

    // ---- epilogue straight from registers ----
    float s9[9];
    #pragma unroll
    for (int q = 0; q < 9; q++) s9[q] = 0.f;
    #pragma unroll
    for (int i = 0; i < 4; i++){
        const float* dmg = demand + b*NN + (ti*TT + r0 + i)*NL + tj*TT;
        float* ttg = out + O_TT + b*NN + (ti*TT + r0 + i)*NL + tj*TT;
        float2 m0 = *(const float2*)(dmg + 2*cA);
        float2 m1 = *(const float2*)(dmg + 2*cB);
        float dmv[4] = {m0.x, m0.y, m1.x, m1.y};
        float tts[4];
        #pragma unroll
        for (int e = 0; e < 4; e++){
            double v = dd[i][e];
            bool np = !(v < 1e37);
            double vv = np ? 0.0 : v;
            int h = (int)(((long long)(vv * H2)) & (long long)HMASK);
            float d = (float)vv;
            float dm = dmv[e];
            float pl = np ? 0.f : (float)(h + 1);
            float tr = (pl == 0.f) ? 0.f : pl - 2.f;
            float tt = np ? 0.f : d + tr*300.f;   // AVG_TRANSFER_WAIT_TIME_S
            tts[e] = tt;
            s9[0] += dm*tt;
            s9[1] += dm*tr;
            s9[2] += np ? dm : 0.f;
            s9[3] += dm;
            s9[4] += (np && dm > 0.f) ? 1.f : 0.f;
            s9[5] += (tr == 0.f) ? dm : 0.f;
            s9[6] += (tr == 1.f) ? dm : 0.f;
            s9[7] += (tr == 2.f) ? dm : 0.f;
            s9[8] += (tr > 2.f) ? dm : 0.f;
        }
        *(float2*)(ttg + 2*cA) = make_float2(tts[0], tts[1]);
        *(float2*)(ttg + 2*cB) = make_float2(tts[2], tts[3]);
    }
    #define RED(x) { x += __shfl_down(x,32); x += __shfl_down(x,16); x += __shfl_down(x,8); \
                     x += __shfl_down(x,4);  x += __shfl_down(x,2);  x += __shfl_down(x,1); }
    #pragma unroll
    for (int q = 0; q < 9; q++) RED(s9[q])
    float* red = (float*)SB;
    int wv = t >> 6;
    if ((t & 63) == 0){
        #pragma unroll
        for (int q = 0; q < 9; q++) red[wv*9 + q] = s9[q];
    }
    __syncthreads();
    if (t < 9){
        float v = red[t] + red[9+t] + red[18+t] + red[27+t];
        int slot = (t == 0) ? 0 : t + 1;
        atomicAdd(&acc[b*16 + slot], v);
    }
    bbar(cbp, 16u*11);
    if (m == 0 && t == 0){
        float a[10];
        #pragma unroll
        for (int q = 0; q < 10; q++) a[q] = acc[b*16 + q];
        out[O_TDT + b] = a[0];
        out[O_RT  + b] = a[1];
        out[O_TAT + 4*b + 0] = a[6];
        out[O_TAT + 4*b + 1] = a[7];
        out[O_TAT + 4*b + 2] = a[8];
        out[O_TAT + 4*b + 3] = a[9] + a[3];
        out[O_TD  + b] = a[4];
        out[O_UNS + b] = a[3];
        out[O_TTR + b] = a[2];
        out[O_ND  + b] = a[5];
    }
}

extern "C" void kernel_launch(void* const* d_in, const int* in_sizes, int n_in,
                              void* d_out, int out_size, void* d_ws, size_t ws_size,
                              hipStream_t stream){
    (void)in_sizes; (void)n_in; (void)out_size; (void)ws_size;
    const float* dtm    = (const float*)d_in[0];
    const float* demand = (const float*)d_in[1];
    const int*   routes = (const int*)d_in[2];
    float* out = (float*)d_out;
    double*   D   = (double*)d_ws;            // packed (dist,hops), 8 MB
    float*    acc = (float*)(D + BNN);        // 256 floats
    unsigned* ctr = (unsigned*)(acc + 256);   // 16 batches x 32-uint stride

    k_init0<<<1, 512, 0, stream>>>(ctr);
    k_mega <<<256, 256, 0, stream>>>(dtm, routes, demand, D, out, acc, ctr);
}

// Round 6
// 251.591 us; speedup vs baseline: 1.3842x; 1.3842x over previous
//
#include <hip/hip_runtime.h>

// Problem constants
#define BB 16
#define NL 256
#define RR 24
#define LL 32
#define NN (NL*NL)        // 65536
#define BNN (BB*NN)       // 1048576
#define TT 64             // FW tile

// Output layout (float32), reference return order.
#define O_TDT 0
#define O_RT  16
#define O_TAT 32
#define O_TD  96
#define O_UNS 112
#define O_TTR 128
#define O_TT  144
#define O_ND  1048720

// Packed (dist, hops) in one f64: v = dist + hops * 2^-30.
// dists exact multiples of 2^-17; hops << 2^13; dist < 2^23 -> packing exact
// in 53-bit mantissa; f64 add distributes; f64 min = lexicographic.
// "Infinity" = qNaN pattern 0x7FF07FF07FF07FF0 (memset-able 4B pattern):
// NaN+x=NaN, IEEE fmin(NaN,x)=x, ull-atomicMin: NaN bits > any finite packed.
#define HSC 9.3132257461547852e-10   // 2^-30
#define H2  1073741824.0             // 2^30
#define HMASK 8191

// LDS: rows of 64 doubles, 16B (double2) chunks XOR-swizzled by row.
#define RIDX(r, c2) (((r)<<6) + ((((c2) ^ ((r)&31)))<<1))
#define LDD(A, r, c2) (*(double2*)&A[RIDX((r),(c2))])

// ---------------- route edges + diag zeros: one wave per (b,r) ---------------
__global__ void k_routes(const float* __restrict__ dtm, const int* __restrict__ routes,
                         unsigned long long* __restrict__ dist, float* __restrict__ acc){
    int br = blockIdx.x; int b = br / RR, r = br % RR;
    int lane = threadIdx.x;
    // diag zeros (first 64 blocks cover 16*256 entries); benign vs atomicMin
    int gid = br*64 + lane;
    if (gid < BB*NL){
        int bq = gid >> 8, n = gid & 255;
        ((double*)dist)[bq*NN + n*(NL+1)] = 0.0;
    }
    __shared__ int   s[LL];
    __shared__ float lf[LL], lr[LL], cf[LL], cr[LL];
    if (lane < LL) s[lane] = routes[(b*RR + r)*LL + lane];
    __syncthreads();
    if (lane < LL-1){
        int a0 = s[lane], a1 = s[lane+1];
        const float* dt = dtm + b*NN;
        lf[lane] = dt[a0*NL + a1] + 60.0f;   // MEAN_STOP_TIME_S
        lr[lane] = dt[a1*NL + a0] + 60.0f;
    }
    __syncthreads();
    if (lane == 0){
        float af = 0.f, ar2 = 0.f;
        cf[0] = 0.f; cr[0] = 0.f;
        for (int l = 0; l < LL-1; l++){
            af += lf[l]; ar2 += lr[l];
            cf[l+1] = af; cr[l+1] = ar2;
        }
        atomicAdd(&acc[b*16 + 1], af + ar2);  // total_route_time
    }
    __syncthreads();
    for (int p = lane; p < LL*LL; p += 64){
        int i = p >> 5, j = p & 31;
        if (j > i){
            double vf = (double)(cf[j] - cf[i]) + HSC;   // hops = 1
            double vr = (double)(cr[j] - cr[i]) + HSC;
            atomicMin(&dist[b*NN + s[i]*NL + s[j]], (unsigned long long)__double_as_longlong(vf));
            atomicMin(&dist[b*NN + s[j]*NL + s[i]], (unsigned long long)__double_as_longlong(vr));
        }
    }
}

// ---------------- one full FW round; FINAL fuses the epilogue ----------------
// dst(ti,tj) = min(D0, C0 (x) K* (x) B0) on packed f64.
// 512 threads, k-split 4x4: lane pair (lane, lane^32) owns the same 4x4 output
// over opposite k-halves; combine = 16x shfl_xor(32)+fmin per multiply.
// 8 waves/CU + 0.25 b128/relax (was: 8 waves @0.375 or 4 waves @0.25).
template<bool FINAL>
__global__ __launch_bounds__(512, 2) void k_fw(
        const double* __restrict__ src, double* __restrict__ dst, int kb,
        const float* __restrict__ demand, float* __restrict__ out,
        float* __restrict__ acc){
    int b  = blockIdx.y;
    int m  = blockIdx.x;
    int ti = m >> 2, tj = m & 3;
    int t  = threadIdx.x;
    int w  = t >> 6, lane = t & 63;
    int kh = lane >> 5, sub = lane & 31;   // k-half, sub-lane
    int cA = sub & 15, cB = cA + 16;       // owned chunks: cols {2cA,2cA+1,2cA+32,2cA+33}
    int r0 = w*8 + (sub >> 4)*4;           // 4 owned rows
    __shared__ __align__(16) double KD[4096];   // K -> K*; later C0
    __shared__ __align__(16) double BD[4096];   // B0; later M = K* (x) B0
    const double* Kg = src + b*NN + kb*TT*(NL+1);
    const double* Bg = src + b*NN + (kb*NL + tj)*TT;
    const double* Cg = src + b*NN + (ti*NL + kb)*TT;
    const double* Dg = src + b*NN + (ti*NL + tj)*TT;

    // ---- early prefetch C0 (staging layout) and D0 (own layout) ----
    double2 c0r[4];
    #pragma unroll
    for (int u = 0; u < 4; u++){
        int fid = u*512 + t, row = fid >> 5, cc = fid & 31;
        c0r[u] = *(const double2*)(Cg + row*NL + cc*2);
    }
    double2 d0a[4], d0b[4];
    #pragma unroll
    for (int i = 0; i < 4; i++){
        d0a[i] = *(const double2*)(Dg + (r0+i)*NL + 2*cA);
        d0b[i] = *(const double2*)(Dg + (r0+i)*NL + 2*cB);
    }

    // ---- stage K and B0 into LDS ----
    #pragma unroll
    for (int u = 0; u < 4; u++){
        int fid = u*512 + t, row = fid >> 5, cc = fid & 31;
        LDD(KD, row, cc) = *(const double2*)(Kg + row*NL + cc*2);
        LDD(BD, row, cc) = *(const double2*)(Bg + row*NL + cc*2);
    }
    __syncthreads();

    // ---- in-LDS hierarchical closure of K (sub-tile 16, 4 sub-rounds) ----
    for (int skb = 0; skb < 4; skb++){
        int s0 = skb*16, sc2 = skb*8;
        // p1: wave 0 closes the 16x16 diag sub-tile via shfl (no barriers)
        if (t < 64){
            int i = t >> 2, jg = t & 3, rr = s0 + i, cbk = sc2 + jg*2;
            double2 m0 = LDD(KD, rr, cbk), m1 = LDD(KD, rr, cbk+1);
            double md4[4] = {m0.x, m0.y, m1.x, m1.y};
            #pragma unroll
            for (int k = 0; k < 16; k++){
                double rd[4];
                #pragma unroll
                for (int c = 0; c < 4; c++) rd[c] = __shfl(md4[c], (k<<2)|jg);
                double cd = __shfl(md4[k&3], (i<<2)|(k>>2));
                #pragma unroll
                for (int c = 0; c < 4; c++) md4[c] = fmin(md4[c], cd + rd[c]);
            }
            LDD(KD, rr, cbk)   = make_double2(md4[0], md4[1]);
            LDD(KD, rr, cbk+1) = make_double2(md4[2], md4[3]);
        }
        __syncthreads();
        // p2: strips, 512 threads, 1x4 each. t<256: row strip (16 band rows x
        // 64 cols); t>=256: col strip (64 rows x 16 band cols). Band-square
        // double-write is a benign same-value race (identical snapshot+formula).
        {
            double sv[4], av[16];
            int pr, pcA, pcB;
            if (t < 256){ pr = s0 + (t >> 4); pcA = t & 15;            pcB = pcA + 16; }
            else        { int t2 = t - 256; pr = t2 >> 2; pcA = sc2 + (t2 & 3); pcB = pcA + 4; }
            double2 v0 = LDD(KD, pr, pcA), v1 = LDD(KD, pr, pcB);
            sv[0]=v0.x; sv[1]=v0.y; sv[2]=v1.x; sv[3]=v1.y;
            #pragma unroll
            for (int c = 0; c < 8; c++){
                double2 a2 = LDD(KD, pr, sc2 + c);
                av[2*c] = a2.x; av[2*c+1] = a2.y;
            }
            #pragma unroll
            for (int k = 0; k < 16; k++){
                double2 b0 = LDD(KD, s0+k, pcA), b1 = LDD(KD, s0+k, pcB);
                sv[0] = fmin(sv[0], av[k] + b0.x);
                sv[1] = fmin(sv[1], av[k] + b0.y);
                sv[2] = fmin(sv[2], av[k] + b1.x);
                sv[3] = fmin(sv[3], av[k] + b1.y);
            }
            __syncthreads();   // all p2 reads done
            LDD(KD, pr, pcA) = make_double2(sv[0], sv[1]);
            LDD(KD, pr, pcB) = make_double2(sv[2], sv[3]);
        }
        __syncthreads();
        // p3: full 64x64, k-split 4x4 over the 16-deep band
        double dd[4][4];
        #pragma unroll
        for (int i = 0; i < 4; i++){
            double2 v0 = LDD(KD, r0+i, cA), v1 = LDD(KD, r0+i, cB);
            dd[i][0]=v0.x; dd[i][1]=v0.y; dd[i][2]=v1.x; dd[i][3]=v1.y;
        }
        #pragma unroll
        for (int q4 = 0; q4 < 2; q4++){
            int kc = sc2 + kh*4 + q4*2;    // a chunk base (band cols of own rows)
            int kr = s0 + kh*8 + q4*4;     // b row base (band rows)
            double a[4][4], bm[4][4];
            #pragma unroll
            for (int i = 0; i < 4; i++){
                double2 a0 = LDD(KD, r0+i, kc), a1 = LDD(KD, r0+i, kc+1);
                a[i][0]=a0.x; a[i][1]=a0.y; a[i][2]=a1.x; a[i][3]=a1.y;
            }
            #pragma unroll
            for (int q = 0; q < 4; q++){
                double2 b0 = LDD(KD, kr+q, cA), b1 = LDD(KD, kr+q, cB);
                bm[q][0]=b0.x; bm[q][1]=b0.y; bm[q][2]=b1.x; bm[q][3]=b1.y;
            }
            #pragma unroll
            for (int q = 0; q < 4; q++)
            #pragma unroll
            for (int i = 0; i < 4; i++)
            #pragma unroll
            for (int j = 0; j < 4; j++)
                dd[i][j] = fmin(dd[i][j], a[i][q] + bm[q][j]);
        }
        #pragma unroll
        for (int i = 0; i < 4; i++)
        #pragma unroll
        for (int j = 0; j < 4; j++)
            dd[i][j] = fmin(dd[i][j], __shfl_xor(dd[i][j], 32));
        __syncthreads();   // all p3 reads done
        #pragma unroll
        for (int i = 0; i < 4; i++){   // both kh halves write same data: benign
            LDD(KD, r0+i, cA) = make_double2(dd[i][0], dd[i][1]);
            LDD(KD, r0+i, cB) = make_double2(dd[i][2], dd[i][3]);
        }
        __syncthreads();
    }

    // ---- M = K* (x) B0 (K* 0-diag -> includes identity), k-split 4x4 ----
    double nanv = __longlong_as_double(0x7FF07FF07FF07FF0LL);
    double md[4][4];
    #pragma unroll
    for (int i = 0; i < 4; i++)
    #pragma unroll
    for (int j = 0; j < 4; j++) md[i][j] = nanv;
    #pragma unroll 2
    for (int q4 = 0; q4 < 8; q4++){
        int kc = kh*16 + q4*2;         // a chunk base
        int kr = kh*32 + q4*4;         // b row base
        double a[4][4], bm[4][4];
        #pragma unroll
        for (int i = 0; i < 4; i++){
            double2 a0 = LDD(KD, r0+i, kc), a1 = LDD(KD, r0+i, kc+1);
            a[i][0]=a0.x; a[i][1]=a0.y; a[i][2]=a1.x; a[i][3]=a1.y;
        }
        #pragma unroll
        for (int q = 0; q < 4; q++){
            double2 b0 = LDD(BD, kr+q, cA), b1 = LDD(BD, kr+q, cB);
            bm[q][0]=b0.x; bm[q][1]=b0.y; bm[q][2]=b1.x; bm[q][3]=b1.y;
        }
        #pragma unroll
        for (int q = 0; q < 4; q++)
        #pragma unroll
        for (int i = 0; i < 4; i++)
        #pragma unroll
        for (int j = 0; j < 4; j++)
            md[i][j] = fmin(md[i][j], a[i][q] + bm[q][j]);
    }
    #pragma unroll
    for (int i = 0; i < 4; i++)
    #pragma unroll
    for (int j = 0; j < 4; j++)
        md[i][j] = fmin(md[i][j], __shfl_xor(md[i][j], 32));
    __syncthreads();   // all K*/B0 reads done
    // write M over B0 (dup-write benign); write prefetched C0 over K*
    #pragma unroll
    for (int i = 0; i < 4; i++){
        LDD(BD, r0+i, cA) = make_double2(md[i][0], md[i][1]);
        LDD(BD, r0+i, cB) = make_double2(md[i][2], md[i][3]);
    }
    #pragma unroll
    for (int u = 0; u < 4; u++){
        int fid = u*512 + t, row = fid >> 5, cc = fid & 31;
        LDD(KD, row, cc) = c0r[u];
    }
    __syncthreads();

    // ---- dst = min(D0, C0 (x) M), k-split 4x4 ----
    double dd[4][4];
    #pragma unroll
    for (int i = 0; i < 4; i++){
        dd[i][0]=d0a[i].x; dd[i][1]=d0a[i].y; dd[i][2]=d0b[i].x; dd[i][3]=d0b[i].y;
    }
    #pragma unroll 2
    for (int q4 = 0; q4 < 8; q4++){
        int kc = kh*16 + q4*2;
        int kr = kh*32 + q4*4;
        double a[4][4], bm[4][4];
        #pragma unroll
        for (int i = 0; i < 4; i++){
            double2 a0 = LDD(KD, r0+i, kc), a1 = LDD(KD, r0+i, kc+1);
            a[i][0]=a0.x; a[i][1]=a0.y; a[i][2]=a1.x; a[i][3]=a1.y;
        }
        #pragma unroll
        for (int q = 0; q < 4; q++){
            double2 b0 = LDD(BD, kr+q, cA), b1 = LDD(BD, kr+q, cB);
            bm[q][0]=b0.x; bm[q][1]=b0.y; bm[q][2]=b1.x; bm[q][3]=b1.y;
        }
        #pragma unroll
        for (int q = 0; q < 4; q++)
        #pragma unroll
        for (int i = 0; i < 4; i++)
        #pragma unroll
        for (int j = 0; j < 4; j++)
            dd[i][j] = fmin(dd[i][j], a[i][q] + bm[q][j]);
    }
    #pragma unroll
    for (int i = 0; i < 4; i++)
    #pragma unroll
    for (int j = 0; j < 4; j++)
        dd[i][j] = fmin(dd[i][j], __shfl_xor(dd[i][j], 32));

    if (!FINAL){
        if (kh == 0){
            double* Od = dst + b*NN + (ti*NL + tj)*TT;
            #pragma unroll
            for (int i = 0; i < 4; i++){
                *(double2*)(Od + (r0+i)*NL + 2*cA) = make_double2(dd[i][0], dd[i][1]);
                *(double2*)(Od + (r0+i)*NL + 2*cB) = make_double2(dd[i][2], dd[i][3]);
            }
        }
        return;
    }

    // ---- fused epilogue (FINAL): no dist write; stats straight from regs ----
    float s9[9];
    #pragma unroll
    for (int q = 0; q < 9; q++) s9[q] = 0.f;
    if (kh == 0){
        #pragma unroll
        for (int i = 0; i < 4; i++){
            const float* dmg = demand + b*NN + (ti*TT + r0 + i)*NL + tj*TT;
            float* ttg = out + O_TT + b*NN + (ti*TT + r0 + i)*NL + tj*TT;
            float2 m0 = *(const float2*)(dmg + 2*cA);
            float2 m1 = *(const float2*)(dmg + 2*cB);
            float dmv[4] = {m0.x, m0.y, m1.x, m1.y};
            float tts[4];
            #pragma unroll
            for (int e = 0; e < 4; e++){
                double v = dd[i][e];
                bool np = !(v < 1e37);
                double vv = np ? 0.0 : v;
                int h = (int)(((long long)(vv * H2)) & (long long)HMASK);
                float d = (float)vv;
                float dm = dmv[e];
                float pl = np ? 0.f : (float)(h + 1);
                float tr = (pl == 0.f) ? 0.f : pl - 2.f;
                float tt = np ? 0.f : d + tr*300.f;   // AVG_TRANSFER_WAIT_TIME_S
                tts[e] = tt;
                s9[0] += dm*tt;
                s9[1] += dm*tr;
                s9[2] += np ? dm : 0.f;
                s9[3] += dm;
                s9[4] += (np && dm > 0.f) ? 1.f : 0.f;
                s9[5] += (tr == 0.f) ? dm : 0.f;
                s9[6] += (tr == 1.f) ? dm : 0.f;
                s9[7] += (tr == 2.f) ? dm : 0.f;
                s9[8] += (tr > 2.f) ? dm : 0.f;
            }
            *(float2*)(ttg + 2*cA) = make_float2(tts[0], tts[1]);
            *(float2*)(ttg + 2*cB) = make_float2(tts[2], tts[3]);
        }
    }
    #define RED(x) { x += __shfl_down(x,32); x += __shfl_down(x,16); x += __shfl_down(x,8); \
                     x += __shfl_down(x,4);  x += __shfl_down(x,2);  x += __shfl_down(x,1); }
    #pragma unroll
    for (int q = 0; q < 9; q++) RED(s9[q])
    __syncthreads();   // done with KD reads; reuse as reduction scratch
    float* red = (float*)KD;
    if (lane == 0){
        #pragma unroll
        for (int q = 0; q < 9; q++) red[w*9 + q] = s9[q];
    }
    __syncthreads();
    if (t < 9){
        float v = 0.f;
        #pragma unroll
        for (int ww = 0; ww < 8; ww++) v += red[ww*9 + t];
        // acc slots: 0 tdt, 1 rt, 2 ttrans, 3 uns, 4 tdem, 5 ndis, 6 b0, 7 b1, 8 b2, 9 bun
        int slot = (t == 0) ? 0 : t + 1;
        atomicAdd(&acc[b*16 + slot], v);
    }
    __syncthreads();
    __shared__ int isLast;
    if (t == 0){
        unsigned prev = atomicAdd((unsigned int*)(acc + 255), 1u);
        isLast = (prev == 255u) ? 1 : 0;   // 256 blocks
    }
    __syncthreads();
    if (isLast && t < BB){
        int bb = t;
        float a[10];
        #pragma unroll
        for (int s = 0; s < 10; s++) a[s] = atomicAdd(&acc[bb*16 + s], 0.f);  // coherent read
        out[O_TDT + bb] = a[0];
        out[O_RT  + bb] = a[1];
        out[O_TAT + 4*bb + 0] = a[6];
        out[O_TAT + 4*bb + 1] = a[7];
        out[O_TAT + 4*bb + 2] = a[8];
        out[O_TAT + 4*bb + 3] = a[9] + a[3];
        out[O_TD  + bb] = a[4];
        out[O_UNS + bb] = a[3];
        out[O_TTR + bb] = a[2];
        out[O_ND  + bb] = a[5];
    }
}

extern "C" void kernel_launch(void* const* d_in, const int* in_sizes, int n_in,
                              void* d_out, int out_size, void* d_ws, size_t ws_size,
                              hipStream_t stream){
    (void)in_sizes; (void)n_in; (void)out_size; (void)ws_size;
    const float* dtm    = (const float*)d_in[0];
    const float* demand = (const float*)d_in[1];
    const int*   routes = (const int*)d_in[2];
    float* out = (float*)d_out;
    double* distA = (double*)d_ws;          // buf0 packed (dist,hops)
    double* distB = distA + BNN;            // buf1 packed
    float*  acc   = (float*)(distB + BNN);  // 256 floats (incl. counter at [255])

    // dist = qNaN pattern ("infinity" for this algebra), acc = 0
    hipMemsetD32Async((hipDeviceptr_t)distA, 0x7FF07FF0u, (size_t)BNN*2, stream);
    hipMemsetAsync(acc, 0, 256*sizeof(float), stream);
    k_routes<<<BB*RR, 64, 0, stream>>>(dtm, routes, (unsigned long long*)distA, acc);
    // 4 rounds, double-buffered; final round fuses the epilogue (no dist write)
    k_fw<false><<<dim3(16,BB), 512, 0, stream>>>(distA, distB, 0, nullptr, nullptr, nullptr);
    k_fw<false><<<dim3(16,BB), 512, 0, stream>>>(distB, distA, 1, nullptr, nullptr, nullptr);
    k_fw<false><<<dim3(16,BB), 512, 0, stream>>>(distA, distB, 2, nullptr, nullptr, nullptr);
    k_fw<true> <<<dim3(16,BB), 512, 0, stream>>>(distB, nullptr, 3, demand, out, acc);
}

// Round 7
// 239.399 us; speedup vs baseline: 1.4546x; 1.0509x over previous
//
#include <hip/hip_runtime.h>

// Problem constants
#define BB 16
#define NL 256
#define RR 24
#define LL 32
#define NN (NL*NL)        // 65536
#define BNN (BB*NN)       // 1048576
#define TT 64             // FW tile

// Output layout (float32), reference return order.
#define O_TDT 0
#define O_RT  16
#define O_TAT 32
#define O_TD  96
#define O_UNS 112
#define O_TTR 128
#define O_TT  144
#define O_ND  1048720

// Packed (dist, hops) in one f64: v = dist + hops * 2^-30.
// dists exact multiples of 2^-17; hops << 2^13; dist < 2^23 -> packing exact
// in 53-bit mantissa; f64 add distributes; f64 min = lexicographic.
// "Infinity" = qNaN pattern 0x7FF07FF07FF07FF0 (memset-able 4B pattern):
// NaN+x=NaN, IEEE fmin(NaN,x)=x, ull-atomicMin: NaN bits > any finite packed.
#define HSC 9.3132257461547852e-10   // 2^-30
#define H2  1073741824.0             // 2^30
#define HMASK 8191

// LDS: rows of 64 doubles, 16B (double2) chunks XOR-swizzled by row.
#define RIDX(r, c2) (((r)<<6) + ((((c2) ^ ((r)&31)))<<1))
#define LDD(A, r, c2) (*(double2*)&A[RIDX((r),(c2))])

// ---------------- route edges + diag zeros: one wave per (b,r) ---------------
__global__ void k_routes(const float* __restrict__ dtm, const int* __restrict__ routes,
                         unsigned long long* __restrict__ dist, float* __restrict__ acc){
    int br = blockIdx.x; int b = br / RR, r = br % RR;
    int lane = threadIdx.x;
    // diag zeros (first 64 blocks cover 16*256 entries); benign vs atomicMin
    int gid = br*64 + lane;
    if (gid < BB*NL){
        int bq = gid >> 8, n = gid & 255;
        ((double*)dist)[bq*NN + n*(NL+1)] = 0.0;
    }
    __shared__ int   s[LL];
    __shared__ float lf[LL], lr[LL], cf[LL], cr[LL];
    if (lane < LL) s[lane] = routes[(b*RR + r)*LL + lane];
    __syncthreads();
    if (lane < LL-1){
        int a0 = s[lane], a1 = s[lane+1];
        const float* dt = dtm + b*NN;
        lf[lane] = dt[a0*NL + a1] + 60.0f;   // MEAN_STOP_TIME_S
        lr[lane] = dt[a1*NL + a0] + 60.0f;
    }
    __syncthreads();
    if (lane == 0){
        float af = 0.f, ar2 = 0.f;
        cf[0] = 0.f; cr[0] = 0.f;
        for (int l = 0; l < LL-1; l++){
            af += lf[l]; ar2 += lr[l];
            cf[l+1] = af; cr[l+1] = ar2;
        }
        atomicAdd(&acc[b*16 + 1], af + ar2);  // total_route_time
    }
    __syncthreads();
    for (int p = lane; p < LL*LL; p += 64){
        int i = p >> 5, j = p & 31;
        if (j > i){
            double vf = (double)(cf[j] - cf[i]) + HSC;   // hops = 1
            double vr = (double)(cr[j] - cr[i]) + HSC;
            atomicMin(&dist[b*NN + s[i]*NL + s[j]], (unsigned long long)__double_as_longlong(vf));
            atomicMin(&dist[b*NN + s[j]*NL + s[i]], (unsigned long long)__double_as_longlong(vr));
        }
    }
}

// ---------------- one full FW round; FINAL fuses the epilogue ----------------
// dst(ti,tj) = min(D0, C0 (x) K* (x) B0) on packed f64; 512 thr, 2x4/thread.
// (R1-proven layout: uniform-row B-reads = broadcast, 2-way conflicts = free.)
template<bool FINAL>
__global__ __launch_bounds__(512) void k_fw(
        const double* __restrict__ src, double* __restrict__ dst, int kb,
        const float* __restrict__ demand, float* __restrict__ out,
        float* __restrict__ acc){
    int b  = blockIdx.y;
    int m  = blockIdx.x;
    int ti = m >> 2, tj = m & 3;
    int t  = threadIdx.x;
    int rp  = (t >> 4) * 2;        // 2 owned rows: rp, rp+1
    int cch = t & 15;              // owned col group (4 cols)
    int c04 = cch * 4;
    __shared__ __align__(16) double KD[4096];   // K -> K*; later C0
    __shared__ __align__(16) double BD[4096];   // B0; later M = K* (x) B0
    const double* Kg = src + b*NN + kb*TT*(NL+1);
    const double* Bg = src + b*NN + (kb*NL + tj)*TT;
    const double* Cg = src + b*NN + (ti*NL + kb)*TT;
    const double* Dg = src + b*NN + (ti*NL + tj)*TT;

    // ---- early prefetch C0 (staging layout) and D0 (own layout) ----
    double2 c0r[4];
    #pragma unroll
    for (int u = 0; u < 4; u++){
        int fid = u*512 + t, row = fid >> 5, cc = fid & 31;
        c0r[u] = *(const double2*)(Cg + row*NL + cc*2);
    }
    double2 d0a[2], d0b[2];
    #pragma unroll
    for (int i = 0; i < 2; i++){
        d0a[i] = *(const double2*)(Dg + (rp+i)*NL + c04);
        d0b[i] = *(const double2*)(Dg + (rp+i)*NL + c04 + 2);
    }

    // ---- stage K and B0 into LDS ----
    #pragma unroll
    for (int u = 0; u < 4; u++){
        int fid = u*512 + t, row = fid >> 5, cc = fid & 31;
        LDD(KD, row, cc) = *(const double2*)(Kg + row*NL + cc*2);
        LDD(BD, row, cc) = *(const double2*)(Bg + row*NL + cc*2);
    }
    __syncthreads();

    // ---- in-LDS hierarchical closure of K (sub-tile 16, 4 sub-rounds) ----
    for (int skb = 0; skb < 4; skb++){
        int s0 = skb*16, sc2 = skb*8;
        // p1: wave 0 closes the 16x16 diag sub-tile via shfl (no barriers)
        if (t < 64){
            int i = t >> 2, jg = t & 3, rr = s0 + i, cbk = sc2 + jg*2;
            double2 m0 = LDD(KD, rr, cbk), m1 = LDD(KD, rr, cbk+1);
            double md4[4] = {m0.x, m0.y, m1.x, m1.y};
            #pragma unroll
            for (int k = 0; k < 16; k++){
                double rd[4];
                #pragma unroll
                for (int c = 0; c < 4; c++) rd[c] = __shfl(md4[c], (k<<2)|jg);
                double cd = __shfl(md4[k&3], (i<<2)|(k>>2));
                #pragma unroll
                for (int c = 0; c < 4; c++) md4[c] = fmin(md4[c], cd + rd[c]);
            }
            LDD(KD, rr, cbk)   = make_double2(md4[0], md4[1]);
            LDD(KD, rr, cbk+1) = make_double2(md4[2], md4[3]);
        }
        __syncthreads();
        // p2: strips, 512 threads, 1x8 each. t<256: row strip (16 band rows x
        // 64 cols); t>=256: col strip (64 rows x 16 band cols). Band-square
        // double-write is a benign same-value race (identical snapshot+formula).
        {
            double sv[4], av[16];
            int pr, pcA, pcB;
            if (t < 256){ pr = s0 + (t >> 4); pcA = t & 15;            pcB = pcA + 16; }
            else        { int t2 = t - 256; pr = t2 >> 2; pcA = sc2 + (t2 & 3); pcB = pcA + 4; }
            double2 v0 = LDD(KD, pr, pcA), v1 = LDD(KD, pr, pcB);
            sv[0]=v0.x; sv[1]=v0.y; sv[2]=v1.x; sv[3]=v1.y;
            #pragma unroll
            for (int c = 0; c < 8; c++){
                double2 a2 = LDD(KD, pr, sc2 + c);
                av[2*c] = a2.x; av[2*c+1] = a2.y;
            }
            #pragma unroll
            for (int k = 0; k < 16; k++){
                double2 b0 = LDD(KD, s0+k, pcA), b1 = LDD(KD, s0+k, pcB);
                sv[0] = fmin(sv[0], av[k] + b0.x);
                sv[1] = fmin(sv[1], av[k] + b0.y);
                sv[2] = fmin(sv[2], av[k] + b1.x);
                sv[3] = fmin(sv[3], av[k] + b1.y);
            }
            __syncthreads();   // all p2 reads done
            LDD(KD, pr, pcA) = make_double2(sv[0], sv[1]);
            LDD(KD, pr, pcB) = make_double2(sv[2], sv[3]);
        }
        __syncthreads();
        // p3: full 64x64, 2x4 per thread, k over the closed 16-band
        double dd[2][4];
        #pragma unroll
        for (int i = 0; i < 2; i++){
            double2 v0 = LDD(KD, rp+i, cch*2), v1 = LDD(KD, rp+i, cch*2+1);
            dd[i][0]=v0.x; dd[i][1]=v0.y; dd[i][2]=v1.x; dd[i][3]=v1.y;
        }
        #pragma unroll
        for (int q4 = 0; q4 < 4; q4++){
            int kr = s0 + q4*4;
            double a[2][4], bm[4][4];
            #pragma unroll
            for (int i = 0; i < 2; i++){
                double2 a0 = LDD(KD, rp+i, sc2+q4*2), a1 = LDD(KD, rp+i, sc2+q4*2+1);
                a[i][0]=a0.x; a[i][1]=a0.y; a[i][2]=a1.x; a[i][3]=a1.y;
            }
            #pragma unroll
            for (int q = 0; q < 4; q++){
                double2 b0 = LDD(KD, kr+q, cch*2), b1 = LDD(KD, kr+q, cch*2+1);
                bm[q][0]=b0.x; bm[q][1]=b0.y; bm[q][2]=b1.x; bm[q][3]=b1.y;
            }
            #pragma unroll
            for (int q = 0; q < 4; q++)
            #pragma unroll
            for (int i = 0; i < 2; i++)
            #pragma unroll
            for (int j = 0; j < 4; j++)
                dd[i][j] = fmin(dd[i][j], a[i][q] + bm[q][j]);
        }
        __syncthreads();   // all p3 reads done
        #pragma unroll
        for (int i = 0; i < 2; i++){
            LDD(KD, rp+i, cch*2)   = make_double2(dd[i][0], dd[i][1]);
            LDD(KD, rp+i, cch*2+1) = make_double2(dd[i][2], dd[i][3]);
        }
        __syncthreads();
    }

    // ---- M = K* (x) B0 (K* 0-diag -> includes identity), 2x4, k-blocked ----
    double nanv = __longlong_as_double(0x7FF07FF07FF07FF0LL);
    double md[2][4];
    #pragma unroll
    for (int i = 0; i < 2; i++)
    #pragma unroll
    for (int j = 0; j < 4; j++) md[i][j] = nanv;
    #pragma unroll 4
    for (int q4 = 0; q4 < 16; q4++){
        int kr = q4*4;
        double a[2][4], bm[4][4];
        #pragma unroll
        for (int i = 0; i < 2; i++){
            double2 a0 = LDD(KD, rp+i, q4*2), a1 = LDD(KD, rp+i, q4*2+1);
            a[i][0]=a0.x; a[i][1]=a0.y; a[i][2]=a1.x; a[i][3]=a1.y;
        }
        #pragma unroll
        for (int q = 0; q < 4; q++){
            double2 b0 = LDD(BD, kr+q, cch*2), b1 = LDD(BD, kr+q, cch*2+1);
            bm[q][0]=b0.x; bm[q][1]=b0.y; bm[q][2]=b1.x; bm[q][3]=b1.y;
        }
        #pragma unroll
        for (int q = 0; q < 4; q++)
        #pragma unroll
        for (int i = 0; i < 2; i++)
        #pragma unroll
        for (int j = 0; j < 4; j++)
            md[i][j] = fmin(md[i][j], a[i][q] + bm[q][j]);
    }
    __syncthreads();   // all K*/B0 reads done
    // write M over B0; write prefetched C0 over K*
    #pragma unroll
    for (int i = 0; i < 2; i++){
        LDD(BD, rp+i, cch*2)   = make_double2(md[i][0], md[i][1]);
        LDD(BD, rp+i, cch*2+1) = make_double2(md[i][2], md[i][3]);
    }
    #pragma unroll
    for (int u = 0; u < 4; u++){
        int fid = u*512 + t, row = fid >> 5, cc = fid & 31;
        LDD(KD, row, cc) = c0r[u];
    }
    __syncthreads();

    // ---- dst = min(D0, C0 (x) M), 2x4, k-blocked ----
    double dd[2][4];
    #pragma unroll
    for (int i = 0; i < 2; i++){
        dd[i][0]=d0a[i].x; dd[i][1]=d0a[i].y; dd[i][2]=d0b[i].x; dd[i][3]=d0b[i].y;
    }
    #pragma unroll 4
    for (int q4 = 0; q4 < 16; q4++){
        int kr = q4*4;
        double a[2][4], bm[4][4];
        #pragma unroll
        for (int i = 0; i < 2; i++){
            double2 a0 = LDD(KD, rp+i, q4*2), a1 = LDD(KD, rp+i, q4*2+1);
            a[i][0]=a0.x; a[i][1]=a0.y; a[i][2]=a1.x; a[i][3]=a1.y;
        }
        #pragma unroll
        for (int q = 0; q < 4; q++){
            double2 b0 = LDD(BD, kr+q, cch*2), b1 = LDD(BD, kr+q, cch*2+1);
            bm[q][0]=b0.x; bm[q][1]=b0.y; bm[q][2]=b1.x; bm[q][3]=b1.y;
        }
        #pragma unroll
        for (int q = 0; q < 4; q++)
        #pragma unroll
        for (int i = 0; i < 2; i++)
        #pragma unroll
        for (int j = 0; j < 4; j++)
            dd[i][j] = fmin(dd[i][j], a[i][q] + bm[q][j]);
    }

    if (!FINAL){
        double* Od = dst + b*NN + (ti*NL + tj)*TT;
        #pragma unroll
        for (int i = 0; i < 2; i++){
            *(double2*)(Od + (rp+i)*NL + c04)     = make_double2(dd[i][0], dd[i][1]);
            *(double2*)(Od + (rp+i)*NL + c04 + 2) = make_double2(dd[i][2], dd[i][3]);
        }
        return;
    }

    // ---- fused epilogue (FINAL): no dist write; stats straight from regs ----
    float s9[9];
    #pragma unroll
    for (int q = 0; q < 9; q++) s9[q] = 0.f;
    #pragma unroll
    for (int i = 0; i < 2; i++){
        const float* dmg = demand + b*NN + (ti*TT + rp + i)*NL + tj*TT;
        float* ttg = out + O_TT + b*NN + (ti*TT + rp + i)*NL + tj*TT;
        float4 mv = *(const float4*)(dmg + c04);
        float dmv[4] = {mv.x, mv.y, mv.z, mv.w};
        float tts[4];
        #pragma unroll
        for (int e = 0; e < 4; e++){
            double v = dd[i][e];
            bool np = !(v < 1e37);
            double vv = np ? 0.0 : v;
            int h = (int)(((long long)(vv * H2)) & (long long)HMASK);
            float d = (float)vv;
            float dm = dmv[e];
            float pl = np ? 0.f : (float)(h + 1);
            float tr = (pl == 0.f) ? 0.f : pl - 2.f;
            float tt = np ? 0.f : d + tr*300.f;   // AVG_TRANSFER_WAIT_TIME_S
            tts[e] = tt;
            s9[0] += dm*tt;
            s9[1] += dm*tr;
            s9[2] += np ? dm : 0.f;
            s9[3] += dm;
            s9[4] += (np && dm > 0.f) ? 1.f : 0.f;
            s9[5] += (tr == 0.f) ? dm : 0.f;
            s9[6] += (tr == 1.f) ? dm : 0.f;
            s9[7] += (tr == 2.f) ? dm : 0.f;
            s9[8] += (tr > 2.f) ? dm : 0.f;
        }
        *(float4*)(ttg + c04) = make_float4(tts[0], tts[1], tts[2], tts[3]);
    }
    #define RED(x) { x += __shfl_down(x,32); x += __shfl_down(x,16); x += __shfl_down(x,8); \
                     x += __shfl_down(x,4);  x += __shfl_down(x,2);  x += __shfl_down(x,1); }
    #pragma unroll
    for (int q = 0; q < 9; q++) RED(s9[q])
    __syncthreads();   // done with KD reads; reuse as reduction scratch
    float* red = (float*)KD;
    int w = t >> 6, lane = t & 63;
    if (lane == 0){
        #pragma unroll
        for (int q = 0; q < 9; q++) red[w*9 + q] = s9[q];
    }
    __syncthreads();
    if (t < 9){
        float v = 0.f;
        #pragma unroll
        for (int ww = 0; ww < 8; ww++) v += red[ww*9 + t];
        // acc slots: 0 tdt, 1 rt, 2 ttrans, 3 uns, 4 tdem, 5 ndis, 6 b0, 7 b1, 8 b2, 9 bun
        int slot = (t == 0) ? 0 : t + 1;
        atomicAdd(&acc[b*16 + slot], v);
    }
    __syncthreads();
    __shared__ int isLast;
    if (t == 0){
        unsigned prev = atomicAdd((unsigned int*)(acc + 255), 1u);
        isLast = (prev == 255u) ? 1 : 0;   // 256 blocks
    }
    __syncthreads();
    if (isLast && t < BB){
        int bb = t;
        float a[10];
        #pragma unroll
        for (int s = 0; s < 10; s++) a[s] = atomicAdd(&acc[bb*16 + s], 0.f);  // coherent read
        out[O_TDT + bb] = a[0];
        out[O_RT  + bb] = a[1];
        out[O_TAT + 4*bb + 0] = a[6];
        out[O_TAT + 4*bb + 1] = a[7];
        out[O_TAT + 4*bb + 2] = a[8];
        out[O_TAT + 4*bb + 3] = a[9] + a[3];
        out[O_TD  + bb] = a[4];
        out[O_UNS + bb] = a[3];
        out[O_TTR + bb] = a[2];
        out[O_ND  + bb] = a[5];
    }
}

extern "C" void kernel_launch(void* const* d_in, const int* in_sizes, int n_in,
                              void* d_out, int out_size, void* d_ws, size_t ws_size,
                              hipStream_t stream){
    (void)in_sizes; (void)n_in; (void)out_size; (void)ws_size;
    const float* dtm    = (const float*)d_in[0];
    const float* demand = (const float*)d_in[1];
    const int*   routes = (const int*)d_in[2];
    float* out = (float*)d_out;
    double* distA = (double*)d_ws;          // buf0 packed (dist,hops)
    double* distB = distA + BNN;            // buf1 packed
    float*  acc   = (float*)(distB + BNN);  // 256 floats (incl. counter at [255])

    // dist = qNaN pattern ("infinity" for this algebra), acc = 0
    hipMemsetD32Async((hipDeviceptr_t)distA, 0x7FF07FF0u, (size_t)BNN*2, stream);
    hipMemsetAsync(acc, 0, 256*sizeof(float), stream);
    k_routes<<<BB*RR, 64, 0, stream>>>(dtm, routes, (unsigned long long*)distA, acc);
    // 4 rounds, double-buffered; final round fuses the epilogue (no dist write)
    k_fw<false><<<dim3(16,BB), 512, 0, stream>>>(distA, distB, 0, nullptr, nullptr, nullptr);
    k_fw<false><<<dim3(16,BB), 512, 0, stream>>>(distB, distA, 1, nullptr, nullptr, nullptr);
    k_fw<false><<<dim3(16,BB), 512, 0, stream>>>(distA, distB, 2, nullptr, nullptr, nullptr);
    k_fw<true> <<<dim3(16,BB), 512, 0, stream>>>(distB, nullptr, 3, demand, out, acc);
}